// Round 6
// baseline (909.895 us; speedup 1.0000x reference)
//
#include <hip/hip_runtime.h>
#include <stdint.h>

#define M_DIM 65536
#define N_DIM 1024
#define K_DIM 256
#define BM 128
#define BN 128
#define BK 64

typedef __attribute__((ext_vector_type(8))) short short8;
typedef __attribute__((ext_vector_type(8))) unsigned short ushort8;
typedef __attribute__((ext_vector_type(16))) float float16;

__device__ __forceinline__ unsigned short f2bf(float f) {
    unsigned u = __builtin_bit_cast(unsigned, f);
    u += 0x7FFFu + ((u >> 16) & 1u);   // round-to-nearest-even
    return (unsigned short)(u >> 16);
}

// ---------------- prep kernel ----------------
// wT layout: [kc(4)][n(1024)][64] bf16 of (-2*w), chunk-swizzled:
//   element (kc, n, k) stored at kc*65536 + n*64 + (((k>>3) ^ (n&7))<<3) + (k&7)
// Parallelized vs r5: 16 blocks (was 4); thread = (kc = tid>>6, n = bid*64 + (tid&63)).
// Same write formula as the verified version, kc-loop distributed across waves;
// per-n sumsq reduced across the 4 kc-waves via LDS (single writer per n).
__global__ __launch_bounds__(256)
void prep_w(const float* __restrict__ w,
            unsigned short* __restrict__ wT,
            float* __restrict__ w_sq) {
    const int tid = threadIdx.x;
    const int kc  = tid >> 6;                  // 0..3 (one wave per kc)
    const int nl  = tid & 63;
    const int n   = blockIdx.x * 64 + nl;      // 16 blocks x 64 cols
    float sq = 0.f;
    #pragma unroll
    for (int c = 0; c < 8; ++c) {
        ushort8 pk;
        #pragma unroll
        for (int j = 0; j < 8; ++j) {
            float v = w[(size_t)(kc * 64 + c * 8 + j) * N_DIM + n]; // coalesced across n
            sq += v * v;
            pk[j] = f2bf(-2.0f * v);
        }
        *(ushort8*)(&wT[kc * 65536 + n * 64 + ((c ^ (n & 7)) << 3)]) = pk;
    }
    __shared__ float red[4][64];
    red[kc][nl] = sq;
    __syncthreads();
    if (tid < 64) {   // kc==0, nl==tid, same n mapping
        w_sq[n] = red[0][nl] + red[1][nl] + red[2][nl] + red[3][nl];
    }
}

// ---------------- main GEMM+epilogue kernel (r5-verified core) ----------------
// Deltas vs verified r5 (each index-level auditable, no new data paths):
//  (1) xsq folded into the xs-alias scratch region: LDS 33280 -> 32768 bytes
//      exactly -> 5 blocks/CU (160 KiB / 32 KiB), was 4. Occupancy +25%.
//  (2) plain stores (nontemporal reverted: r5 showed WRITE_SIZE +22% with nt;
//      r1 plain stores wrote exactly 268 MB).
__global__ __launch_bounds__(256, 5)
void gemm_rbf(const float* __restrict__ x,
              const unsigned short* __restrict__ wT,
              const float* __restrict__ w_sq,
              float* __restrict__ out) {
    __shared__ unsigned short xs[BM * BK];   // swizzled [row][64] bf16, 16 KB
    __shared__ unsigned short ws[BN * BK];   // swizzled [col][64] bf16, 16 KB
    // Scratch aliased onto xs (dead after K-loop, barrier-separated):
    //   xsq_p: 16*132*4 = 8448 B at offset 0
    //   xsq  : 128*4    =  512 B at offset 8448   (total 8960 <= 16384)
    float (*xsq_p)[132] = (float (*)[132])xs;
    float* xsq = (float*)xs + 2112;          // 2112 floats = 8448 bytes

    const int tid  = threadIdx.x;
    const int lane = tid & 63;
    const int wave = tid >> 6;
    const int wy = wave >> 1, wx = wave & 1;  // 2x2 wave grid
    const int l31 = lane & 31;
    const int lhi = lane >> 5;

    // XCD-bijective swizzle (bid in [0,4096), 8 XCDs round-robin on bid&7):
    // XCD k gets logical tiles [k*512, (k+1)*512); 8 consecutive logicals share
    // one m-tile -> the 128 KB x-tile stays in that XCD's L2 (verified r5:
    // FETCH 263 MB -> 58 MB).
    const int bid = blockIdx.x;
    const int lgc = (bid & 7) * 512 + (bid >> 3);
    const int m0  = (lgc >> 3) * BM;
    const int n0  = (lgc & 7) * BN;

    float16 acc[2][2];
    #pragma unroll
    for (int ty = 0; ty < 2; ++ty)
        #pragma unroll
        for (int tx = 0; tx < 2; ++tx)
            #pragma unroll
            for (int i = 0; i < 16; ++i) acc[ty][tx][i] = 0.f;

    float xpart[8];
    #pragma unroll
    for (int p = 0; p < 8; ++p) xpart[p] = 0.f;

    const int xr = tid >> 4;   // base row 0..15 (rows xr + 16p)
    const int xc = tid & 15;   // float4 column group

    for (int kt = 0; kt < 4; ++kt) {
        __syncthreads();   // protect LDS from previous iteration's readers
        // stage ws: identity copy of contiguous 16 KB (swizzle pre-baked in global)
        {
            const uint4* __restrict__ src = (const uint4*)(wT + (size_t)kt * 65536 + (size_t)n0 * 64);
            uint4* dst = (uint4*)ws;
            #pragma unroll
            for (int i = 0; i < 4; ++i) dst[tid * 4 + i] = src[tid * 4 + i];
        }
        // stage xs: fp32 load (coalesced 256B per 16 lanes) -> fp32 sumsq -> bf16 -> swizzled LDS
        {
            #pragma unroll
            for (int p = 0; p < 8; ++p) {
                const int r = xr + p * 16;
                const float4 v = *(const float4*)(x + (size_t)(m0 + r) * K_DIM + kt * BK + xc * 4);
                xpart[p] += v.x * v.x + v.y * v.y + v.z * v.z + v.w * v.w;
                uint2 pk;
                pk.x = (unsigned)f2bf(v.x) | ((unsigned)f2bf(v.y) << 16);
                pk.y = (unsigned)f2bf(v.z) | ((unsigned)f2bf(v.w) << 16);
                char* dst = (char*)xs + r * 128 + (((xc >> 1) ^ (r & 7)) << 4) + ((xc & 1) << 3);
                *(uint2*)dst = pk;
            }
        }
        __syncthreads();
        // MFMA over this K-chunk: 4 steps of K=16
        const int arow0 = wy * 64 + l31;
        const int bcol0 = wx * 64 + l31;
        #pragma unroll
        for (int ks = 0; ks < 4; ++ks) {
            const int c = ks * 2 + lhi;      // logical 16B chunk index in row
            short8 a[2], b[2];
            #pragma unroll
            for (int ty = 0; ty < 2; ++ty) {
                const int r = arow0 + ty * 32;
                a[ty] = *(const short8*)((const char*)xs + r * 128 + ((c ^ (r & 7)) << 4));
            }
            #pragma unroll
            for (int tx = 0; tx < 2; ++tx) {
                const int cc = bcol0 + tx * 32;
                b[tx] = *(const short8*)((const char*)ws + cc * 128 + ((c ^ (cc & 7)) << 4));
            }
            #pragma unroll
            for (int ty = 0; ty < 2; ++ty)
                #pragma unroll
                for (int tx = 0; tx < 2; ++tx)
                    acc[ty][tx] = __builtin_amdgcn_mfma_f32_32x32x16_bf16(
                        a[ty], b[tx], acc[ty][tx], 0, 0, 0);
        }
    }

    // xs is dead from here on; barrier before reusing its space as scratch.
    __syncthreads();

    // reduce per-row sum-of-squares of x (fp32, from original fp32 x)
    #pragma unroll
    for (int p = 0; p < 8; ++p) xsq_p[xc][xr + p * 16] = xpart[p];
    __syncthreads();
    if (tid < BM) {
        float s = 0.f;
        #pragma unroll
        for (int c = 0; c < 16; ++c) s += xsq_p[c][tid];
        xsq[tid] = s;
    }
    __syncthreads();

    // epilogue: out = xsq[row] + acc + wsq[col]   (acc already includes -2 factor)
    float wsqv[2];
    #pragma unroll
    for (int tx = 0; tx < 2; ++tx) wsqv[tx] = w_sq[n0 + wx * 64 + tx * 32 + l31];

    #pragma unroll
    for (int ty = 0; ty < 2; ++ty) {
        const int rbase = wy * 64 + ty * 32 + 4 * lhi;
        float xv[16];
        #pragma unroll
        for (int i = 0; i < 16; ++i) xv[i] = xsq[rbase + (i & 3) + 8 * (i >> 2)];
        #pragma unroll
        for (int tx = 0; tx < 2; ++tx) {
            const int col = n0 + wx * 64 + tx * 32 + l31;
            #pragma unroll
            for (int i = 0; i < 16; ++i) {
                const int row = m0 + rbase + (i & 3) + 8 * (i >> 2);
                out[(size_t)row * N_DIM + col] = xv[i] + acc[ty][tx][i] + wsqv[tx];
            }
        }
    }
}

// ---------------- fallback (only if workspace too small) ----------------
__global__ void fallback_k(const float* __restrict__ x, const float* __restrict__ w,
                           float* __restrict__ out) {
    __shared__ float xrow[K_DIM];
    const int b = blockIdx.x;
    xrow[threadIdx.x] = x[(size_t)b * K_DIM + threadIdx.x];
    __syncthreads();
    for (int g = 0; g < 4; ++g) {
        const int u = g * 256 + threadIdx.x;
        float s = 0.f;
        for (int k = 0; k < K_DIM; ++k) {
            const float d = xrow[k] - w[(size_t)k * N_DIM + u];
            s += d * d;
        }
        out[(size_t)b * N_DIM + u] = s;
    }
}

extern "C" void kernel_launch(void* const* d_in, const int* in_sizes, int n_in,
                              void* d_out, int out_size, void* d_ws, size_t ws_size,
                              hipStream_t stream) {
    const float* x = (const float*)d_in[0];
    const float* w = (const float*)d_in[1];
    float* out = (float*)d_out;

    const size_t wT_bytes = (size_t)4 * 1024 * 64 * 2;  // 512 KB
    const size_t need = wT_bytes + N_DIM * sizeof(float);
    if (ws_size < need) {
        fallback_k<<<M_DIM, 256, 0, stream>>>(x, w, out);
        return;
    }
    unsigned short* wT = (unsigned short*)d_ws;
    float* w_sq = (float*)((char*)d_ws + wT_bytes);

    prep_w<<<16, 256, 0, stream>>>(w, wT, w_sq);
    gemm_rbf<<<(M_DIM / BM) * (N_DIM / BN), 256, 0, stream>>>(x, wT, w_sq, out);
}

// Round 8
// 434.421 us; speedup vs baseline: 2.0945x; 2.0945x over previous
//
#include <hip/hip_runtime.h>
#include <stdint.h>

#define M_DIM 65536
#define N_DIM 1024
#define K_DIM 256
#define BM 128
#define BN 128
#define BK 64

typedef __attribute__((ext_vector_type(8))) short short8;
typedef __attribute__((ext_vector_type(8))) unsigned short ushort8;
typedef __attribute__((ext_vector_type(16))) float float16;

__device__ __forceinline__ unsigned short f2bf(float f) {
    unsigned u = __builtin_bit_cast(unsigned, f);
    u += 0x7FFFu + ((u >> 16) & 1u);   // round-to-nearest-even
    return (unsigned short)(u >> 16);
}

// ---------------- prep kernel ----------------
// wT layout: [kc(4)][n(1024)][64] bf16 of (-2*w), chunk-swizzled:
//   element (kc, n, k) stored at kc*65536 + n*64 + (((k>>3) ^ (n&7))<<3) + (k&7)
// 16 blocks; thread = (kc = tid>>6, n = bid*64 + (tid&63)); per-n sumsq
// reduced across the 4 kc-waves via LDS (single writer per n).
__global__ __launch_bounds__(256)
void prep_w(const float* __restrict__ w,
            unsigned short* __restrict__ wT,
            float* __restrict__ w_sq) {
    const int tid = threadIdx.x;
    const int kc  = tid >> 6;                  // 0..3 (one wave per kc)
    const int nl  = tid & 63;
    const int n   = blockIdx.x * 64 + nl;      // 16 blocks x 64 cols
    float sq = 0.f;
    #pragma unroll
    for (int c = 0; c < 8; ++c) {
        ushort8 pk;
        #pragma unroll
        for (int j = 0; j < 8; ++j) {
            float v = w[(size_t)(kc * 64 + c * 8 + j) * N_DIM + n]; // coalesced across n
            sq += v * v;
            pk[j] = f2bf(-2.0f * v);
        }
        *(ushort8*)(&wT[kc * 65536 + n * 64 + ((c ^ (n & 7)) << 3)]) = pk;
    }
    __shared__ float red[4][64];
    red[kc][nl] = sq;
    __syncthreads();
    if (tid < 64) {   // kc==0, nl==tid, same n mapping
        w_sq[n] = red[0][nl] + red[1][nl] + red[2][nl] + red[3][nl];
    }
}

// ---------------- main GEMM+epilogue kernel ----------------
// Deltas vs r6 (each auditable):
//  (1) launch_bounds back to (256,4): r6's (256,5) squeezed VGPR 64->48 and
//      spilled accumulators (WRITE 1.77 GB, FETCH 827 MB). LDS stays 32768 B
//      so hardware may still place 5 blocks/CU if registers permit.
//  (2) ws stage reindexed dst[tid*4+i] -> dst[i*256+tid]: old form had each
//      lane writing 16 B at 64-B stride (lanes 128 B apart = same bank ->
//      ~10.7M conflict cycles). New form: consecutive lanes write consecutive
//      16 B -> conflict-free ds_write_b128 and perfectly contiguous global
//      reads. Bijective over the same 16 KB, src idx == dst idx.
__global__ __launch_bounds__(256, 4)
void gemm_rbf(const float* __restrict__ x,
              const unsigned short* __restrict__ wT,
              const float* __restrict__ w_sq,
              float* __restrict__ out) {
    __shared__ unsigned short xs[BM * BK];   // swizzled [row][64] bf16, 16 KB
    __shared__ unsigned short ws[BN * BK];   // swizzled [col][64] bf16, 16 KB
    // Scratch aliased onto xs (dead after K-loop, barrier-separated):
    //   xsq_p: 16*132*4 = 8448 B at offset 0
    //   xsq  : 128*4    =  512 B at offset 8448   (total 8960 <= 16384)
    float (*xsq_p)[132] = (float (*)[132])xs;
    float* xsq = (float*)xs + 2112;          // 2112 floats = 8448 bytes

    const int tid  = threadIdx.x;
    const int lane = tid & 63;
    const int wave = tid >> 6;
    const int wy = wave >> 1, wx = wave & 1;  // 2x2 wave grid
    const int l31 = lane & 31;
    const int lhi = lane >> 5;

    // XCD-bijective swizzle (bid in [0,4096), 8 XCDs round-robin on bid&7):
    // XCD k gets logical tiles [k*512, (k+1)*512); 8 consecutive logicals share
    // one m-tile -> the 128 KB x-tile stays in that XCD's L2 (verified r5:
    // FETCH 263 MB -> 58 MB).
    const int bid = blockIdx.x;
    const int lgc = (bid & 7) * 512 + (bid >> 3);
    const int m0  = (lgc >> 3) * BM;
    const int n0  = (lgc & 7) * BN;

    float16 acc[2][2];
    #pragma unroll
    for (int ty = 0; ty < 2; ++ty)
        #pragma unroll
        for (int tx = 0; tx < 2; ++tx)
            #pragma unroll
            for (int i = 0; i < 16; ++i) acc[ty][tx][i] = 0.f;

    float xpart[8];
    #pragma unroll
    for (int p = 0; p < 8; ++p) xpart[p] = 0.f;

    const int xr = tid >> 4;   // base row 0..15 (rows xr + 16p)
    const int xc = tid & 15;   // float4 column group

    for (int kt = 0; kt < 4; ++kt) {
        __syncthreads();   // protect LDS from previous iteration's readers
        // stage ws: identity copy of contiguous 16 KB (swizzle pre-baked in global)
        {
            const uint4* __restrict__ src = (const uint4*)(wT + (size_t)kt * 65536 + (size_t)n0 * 64);
            uint4* dst = (uint4*)ws;
            #pragma unroll
            for (int i = 0; i < 4; ++i) dst[i * 256 + tid] = src[i * 256 + tid];
        }
        // stage xs: fp32 load (coalesced 256B per 16 lanes) -> fp32 sumsq -> bf16 -> swizzled LDS
        {
            #pragma unroll
            for (int p = 0; p < 8; ++p) {
                const int r = xr + p * 16;
                const float4 v = *(const float4*)(x + (size_t)(m0 + r) * K_DIM + kt * BK + xc * 4);
                xpart[p] += v.x * v.x + v.y * v.y + v.z * v.z + v.w * v.w;
                uint2 pk;
                pk.x = (unsigned)f2bf(v.x) | ((unsigned)f2bf(v.y) << 16);
                pk.y = (unsigned)f2bf(v.z) | ((unsigned)f2bf(v.w) << 16);
                char* dst = (char*)xs + r * 128 + (((xc >> 1) ^ (r & 7)) << 4) + ((xc & 1) << 3);
                *(uint2*)dst = pk;
            }
        }
        __syncthreads();
        // MFMA over this K-chunk: 4 steps of K=16
        const int arow0 = wy * 64 + l31;
        const int bcol0 = wx * 64 + l31;
        #pragma unroll
        for (int ks = 0; ks < 4; ++ks) {
            const int c = ks * 2 + lhi;      // logical 16B chunk index in row
            short8 a[2], b[2];
            #pragma unroll
            for (int ty = 0; ty < 2; ++ty) {
                const int r = arow0 + ty * 32;
                a[ty] = *(const short8*)((const char*)xs + r * 128 + ((c ^ (r & 7)) << 4));
            }
            #pragma unroll
            for (int tx = 0; tx < 2; ++tx) {
                const int cc = bcol0 + tx * 32;
                b[tx] = *(const short8*)((const char*)ws + cc * 128 + ((c ^ (cc & 7)) << 4));
            }
            #pragma unroll
            for (int ty = 0; ty < 2; ++ty)
                #pragma unroll
                for (int tx = 0; tx < 2; ++tx)
                    acc[ty][tx] = __builtin_amdgcn_mfma_f32_32x32x16_bf16(
                        a[ty], b[tx], acc[ty][tx], 0, 0, 0);
        }
    }

    // xs is dead from here on; barrier before reusing its space as scratch.
    __syncthreads();

    // reduce per-row sum-of-squares of x (fp32, from original fp32 x)
    #pragma unroll
    for (int p = 0; p < 8; ++p) xsq_p[xc][xr + p * 16] = xpart[p];
    __syncthreads();
    if (tid < BM) {
        float s = 0.f;
        #pragma unroll
        for (int c = 0; c < 16; ++c) s += xsq_p[c][tid];
        xsq[tid] = s;
    }
    __syncthreads();

    // epilogue: out = xsq[row] + acc + wsq[col]   (acc already includes -2 factor)
    float wsqv[2];
    #pragma unroll
    for (int tx = 0; tx < 2; ++tx) wsqv[tx] = w_sq[n0 + wx * 64 + tx * 32 + l31];

    #pragma unroll
    for (int ty = 0; ty < 2; ++ty) {
        const int rbase = wy * 64 + ty * 32 + 4 * lhi;
        float xv[16];
        #pragma unroll
        for (int i = 0; i < 16; ++i) xv[i] = xsq[rbase + (i & 3) + 8 * (i >> 2)];
        #pragma unroll
        for (int tx = 0; tx < 2; ++tx) {
            const int col = n0 + wx * 64 + tx * 32 + l31;
            #pragma unroll
            for (int i = 0; i < 16; ++i) {
                const int row = m0 + rbase + (i & 3) + 8 * (i >> 2);
                out[(size_t)row * N_DIM + col] = xv[i] + acc[ty][tx][i] + wsqv[tx];
            }
        }
    }
}

// ---------------- fallback (only if workspace too small) ----------------
__global__ void fallback_k(const float* __restrict__ x, const float* __restrict__ w,
                           float* __restrict__ out) {
    __shared__ float xrow[K_DIM];
    const int b = blockIdx.x;
    xrow[threadIdx.x] = x[(size_t)b * K_DIM + threadIdx.x];
    __syncthreads();
    for (int g = 0; g < 4; ++g) {
        const int u = g * 256 + threadIdx.x;
        float s = 0.f;
        for (int k = 0; k < K_DIM; ++k) {
            const float d = xrow[k] - w[(size_t)k * N_DIM + u];
            s += d * d;
        }
        out[(size_t)b * N_DIM + u] = s;
    }
}

extern "C" void kernel_launch(void* const* d_in, const int* in_sizes, int n_in,
                              void* d_out, int out_size, void* d_ws, size_t ws_size,
                              hipStream_t stream) {
    const float* x = (const float*)d_in[0];
    const float* w = (const float*)d_in[1];
    float* out = (float*)d_out;

    const size_t wT_bytes = (size_t)4 * 1024 * 64 * 2;  // 512 KB
    const size_t need = wT_bytes + N_DIM * sizeof(float);
    if (ws_size < need) {
        fallback_k<<<M_DIM, 256, 0, stream>>>(x, w, out);
        return;
    }
    unsigned short* wT = (unsigned short*)d_ws;
    float* w_sq = (float*)((char*)d_ws + wT_bytes);

    prep_w<<<16, 256, 0, stream>>>(w, wT, w_sq);
    gemm_rbf<<<(M_DIM / BM) * (N_DIM / BN), 256, 0, stream>>>(x, wT, w_sq, out);
}